// Round 7
// baseline (90.308 us; speedup 1.0000x reference)
//
#include <hip/hip_runtime.h>
#include <stdint.h>

// Tropical (max-plus) matmul: Y[b][j] = max_k X[b][k] + W[j][k]
// M=512, N=1024, K=1024, fp32 in/out. (max,+) -> no MFMA, VALU only.
//
// R6 post-mortem: mm stuck at ~37us across 4 inner-loop variants -> the
// per-tile stage/barrier structure (vmcnt(0)+s_barrier drain every BK=32)
// is the bottleneck, not the pipes. R7 restructure:
//   pass 1: transpose W -> Wt[k][j] fp16 in d_ws (j-contiguous rows)
//   pass 2: mm streams Wt global->VGPR (coalesced uint4, L2-resident, no LDS),
//           X slice staged to LDS ONCE per block (dup-packed (x,x) words),
//           then a barrier-free unrolled loop: 4k = 4 VMEM + 4 DS-broadcast
//           + 128 v_pk instrs. S=16 split-K -> 16 waves/CU.
//   pass 3: max-combine partials.

typedef _Float16 h1;
typedef _Float16 __attribute__((ext_vector_type(2))) h2;
typedef __fp16 __attribute__((ext_vector_type(2))) fp16x2;  // cvt_pkrtz return

#define M_DIM 512
#define N_DIM 1024
#define K_DIM 1024

__device__ __forceinline__ uint32_t pk_add(uint32_t a, uint32_t b) {
    uint32_t d;
    asm("v_pk_add_f16 %0, %1, %2" : "=v"(d) : "v"(a), "v"(b));
    return d;
}
__device__ __forceinline__ uint32_t pk_max(uint32_t a, uint32_t b) {
    uint32_t d;
    asm("v_pk_max_f16 %0, %1, %2" : "=v"(d) : "v"(a), "v"(b));
    return d;
}
__device__ __forceinline__ uint32_t pkrtz(float a, float b) {
    fp16x2 p = __builtin_amdgcn_cvt_pkrtz(a, b);
    return __builtin_bit_cast(uint32_t, p);
}

// ---- pass 1: Wt[k][j] (fp16) <- W[j][k] (fp32), 64x64 tiles via LDS ----
__global__ __launch_bounds__(256)
void transpose_w(const float* __restrict__ W, uint16_t* __restrict__ Wt) {
    __shared__ uint32_t Lt[64][36];  // [j][k-pair word]; stride 36 words = 144B (16B-aligned)

    const int tid = threadIdx.x;
    const int k0 = blockIdx.x * 64;
    const int j0 = blockIdx.y * 64;

    // load: row r (j), 16 k's per thread -> 8 packed words
    {
        const int r  = tid >> 2;            // 0..63
        const int cg = (tid & 3) * 16;      // k offset 0,16,32,48
        const float* g = &W[(size_t)(j0 + r) * K_DIM + k0 + cg];
        float4 f0 = *(const float4*)(g + 0);
        float4 f1 = *(const float4*)(g + 4);
        float4 f2 = *(const float4*)(g + 8);
        float4 f3 = *(const float4*)(g + 12);
        uint4 a = {pkrtz(f0.x, f0.y), pkrtz(f0.z, f0.w), pkrtz(f1.x, f1.y), pkrtz(f1.z, f1.w)};
        uint4 b = {pkrtz(f2.x, f2.y), pkrtz(f2.z, f2.w), pkrtz(f3.x, f3.y), pkrtz(f3.z, f3.w)};
        *(uint4*)&Lt[r][(tid & 3) * 8 + 0] = a;
        *(uint4*)&Lt[r][(tid & 3) * 8 + 4] = b;
    }
    __syncthreads();
    // write: k-pair kp, 8 j's per thread -> two output rows (k even/odd)
    {
        const int kp = tid >> 3;            // 0..31
        const int jg = (tid & 7) * 8;       // 0..56
        uint32_t w[8];
#pragma unroll
        for (int i = 0; i < 8; i++) w[i] = Lt[jg + i][kp];
        uint4 lo, hi;
        uint32_t* lop = (uint32_t*)&lo;
        uint32_t* hip = (uint32_t*)&hi;
#pragma unroll
        for (int i = 0; i < 4; i++) {
            uint32_t we = w[2 * i], wo = w[2 * i + 1];
            lop[i] = (we & 0xFFFFu) | (wo << 16);            // k even halves
            hip[i] = (we >> 16) | (wo & 0xFFFF0000u);        // k odd halves
        }
        uint16_t* r0 = Wt + (size_t)(k0 + 2 * kp) * N_DIM + j0 + jg;
        *(uint4*)r0 = lo;
        *(uint4*)(r0 + N_DIM) = hi;
    }
}

// ---- pass 2: barrier-free W-streaming mm ----
__global__ __launch_bounds__(256, 4)
void tropical_mm_ws(const float* __restrict__ X, const uint16_t* __restrict__ Wt,
                    float* __restrict__ out, int Kper) {
    // X slice: 8 b's, up to 128 k's, dup-packed (x,x) per k
    __shared__ uint32_t Xd[8][128];

    const int tid  = threadIdx.x;
    const int wv   = tid >> 6;          // wave 0..3
    const int lane = tid & 63;
    const int jbase = (wv & 1) * 512 + lane * 8;   // 8 j's per thread
    const int bg    = (wv >> 1) * 4;               // b-group 0 or 4
    const int bb    = blockIdx.x * 8;              // 64 b-blocks
    const int sb    = blockIdx.y;                  // split-K slice
    const int k0    = sb * Kper;

    const uint32_t NEGP = 0xFBFFFBFFu;  // packed (-65504, -65504)
    uint32_t acc[4][4];                 // [b][j-pair word]
#pragma unroll
    for (int b = 0; b < 4; b++)
#pragma unroll
        for (int w = 0; w < 4; w++) acc[b][w] = NEGP;

    for (int kc = 0; kc < Kper; kc += 128) {
        const int kn = (Kper - kc < 128) ? (Kper - kc) : 128;
        if (kc) __syncthreads();
        // stage X: 8*kn dup-packed words, kn/32 per thread (2 or 4)
        {
            const int b  = tid >> 5;                 // 0..7
            const int nw = kn >> 5;                  // 2 or 4
            const int kk = (tid & 31) * nw;          // local k
            const float* g = &X[(size_t)(bb + b) * K_DIM + k0 + kc + kk];
            if (nw == 4) {
                float4 f = *(const float4*)g;
                uint4 v = {pkrtz(f.x, f.x), pkrtz(f.y, f.y), pkrtz(f.z, f.z), pkrtz(f.w, f.w)};
                *(uint4*)&Xd[b][kk] = v;
            } else {
                float2 f = *(const float2*)g;
                uint2 v = {pkrtz(f.x, f.x), pkrtz(f.y, f.y)};
                *(uint2*)&Xd[b][kk] = v;
            }
        }
        __syncthreads();

        // barrier-free streamed inner loop: per 4 k's:
        //   4 global uint4 (Wt rows, coalesced) + 4 ds_read_b128 (broadcast)
        //   + 128 v_pk instrs
        const uint16_t* wrow = Wt + (size_t)(k0 + kc) * N_DIM + jbase;
#pragma unroll 4
        for (int kq = 0; kq < kn; kq += 4) {
            uint4 xb[4];
#pragma unroll
            for (int b = 0; b < 4; b++) xb[b] = *(const uint4*)&Xd[bg + b][kq];
            uint4 w4[4];
#pragma unroll
            for (int t = 0; t < 4; t++)
                w4[t] = *(const uint4*)(wrow + (size_t)(kq + t) * N_DIM);
#pragma unroll
            for (int t = 0; t < 4; t++) {
                const uint32_t* wp = (const uint32_t*)&w4[t];
#pragma unroll
                for (int b = 0; b < 4; b++) {
                    const uint32_t x = ((const uint32_t*)&xb[b])[t];
#pragma unroll
                    for (int w = 0; w < 4; w++)
                        acc[b][w] = pk_max(acc[b][w], pk_add(x, wp[w]));
                }
            }
        }
    }

    // epilogue: unpack j-pairs to fp32, write partial slice (coalesced float4 x2)
    float* dst = out + (size_t)sb * M_DIM * N_DIM;
#pragma unroll
    for (int b = 0; b < 4; b++) {
        float* row = dst + (size_t)(bb + bg + b) * N_DIM + jbase;
#pragma unroll
        for (int half = 0; half < 2; half++) {
            h2 v0 = __builtin_bit_cast(h2, acc[b][2 * half + 0]);
            h2 v1 = __builtin_bit_cast(h2, acc[b][2 * half + 1]);
            float4 o = {(float)v0[0], (float)v0[1], (float)v1[0], (float)v1[1]};
            *(float4*)(row + 4 * half) = o;
        }
    }
}

__global__ __launch_bounds__(256)
void combine_max_kernel(const float* __restrict__ part, float* __restrict__ out, int S) {
    const int idx = blockIdx.x * blockDim.x + threadIdx.x;  // over float4s
    const size_t stride = (size_t)M_DIM * N_DIM;
    float4 a = ((const float4*)part)[idx];
    for (int s = 1; s < S; s++) {
        float4 b = ((const float4*)(part + (size_t)s * stride))[idx];
        a.x = fmaxf(a.x, b.x);
        a.y = fmaxf(a.y, b.y);
        a.z = fmaxf(a.z, b.z);
        a.w = fmaxf(a.w, b.w);
    }
    ((float4*)out)[idx] = a;
}

extern "C" void kernel_launch(void* const* d_in, const int* in_sizes, int n_in,
                              void* d_out, int out_size, void* d_ws, size_t ws_size,
                              hipStream_t stream) {
    const float* X = (const float*)d_in[0];   // [512][1024]
    const float* W = (const float*)d_in[1];   // [1024][1024]
    float* out = (float*)d_out;               // [512][1024]

    const size_t wt_bytes = (size_t)K_DIM * N_DIM * sizeof(uint16_t);  // 2 MB
    const size_t slice_bytes = (size_t)M_DIM * N_DIM * sizeof(float);  // 2 MB

    uint16_t* Wt = (uint16_t*)d_ws;
    float* part = (float*)((char*)d_ws + wt_bytes);

    int S;  // ws observed ~256 MB; need wt + S*slice
    if (ws_size >= wt_bytes + 16 * slice_bytes)     S = 16;
    else if (ws_size >= wt_bytes + 8 * slice_bytes) S = 8;
    else if (ws_size >= wt_bytes + 4 * slice_bytes) S = 4;
    else if (ws_size >= wt_bytes + 2 * slice_bytes) S = 2;
    else                                            S = 1;

    const int Kper = K_DIM / S;
    float* target = (S == 1) ? out : part;

    transpose_w<<<dim3(K_DIM / 64, N_DIM / 64), 256, 0, stream>>>(W, Wt);
    tropical_mm_ws<<<dim3(M_DIM / 8, S), 256, 0, stream>>>(X, Wt, target, Kper);
    if (S > 1) {
        const int n4 = M_DIM * N_DIM / 4;  // 131072 float4
        combine_max_kernel<<<n4 / 256, 256, 0, stream>>>(part, out, S);
    }
}